// Round 7
// baseline (1228.784 us; speedup 1.0000x reference)
//
#include <hip/hip_runtime.h>

// Fused 3-branch shared LSTM(H1=3) -> LSTM(H2=9) -> dense(3)+sigmoid, T=2048, B=1024.
// R7 restructure: LANE-PER-CHAIN. Each lane runs one (batch, chunk) chain entirely:
// no cross-lane traffic at all. 64 chains/wave; LSTM2 weights broadcast-read from LDS
// (uniform address = conflict-free); LSTM1 + dense weights in registers.
// KC=64 chunks x 32 steps, WARMUP=32 (forget-gate contraction ~ e^-20; chunk 0 exact).
// Grid: 256 blocks x 256 thr = 1024 waves = 1 wave/SIMD exactly, zero tail.
// waves_per_eu(1,1): full register budget, no AGPR spill shuttle.

#define SEQT   2048
#define KC     64
#define CHUNK  32          // SEQT / KC
#define WARMUP 32

typedef float f32x2 __attribute__((ext_vector_type(2)));
typedef float f32x4 __attribute__((ext_vector_type(4)));

__device__ __forceinline__ float fexp2(float v) { return __builtin_amdgcn_exp2f(v); }
__device__ __forceinline__ float frcp(float v)  { return __builtin_amdgcn_rcpf(v); }

// Sigmoid-LSTM cell update, all inputs pre-scaled by SS = -log2(e).
// zA=(z_i,z_f)*SS, zB=(z_g,z_o)*SS, cm = SS*c. Returns h = o * sigmoid(c).
__device__ __forceinline__ float cellup(f32x2 zA, f32x2 zB, float& cm) {
    const float eI = fexp2(zA.x), eF = fexp2(zA.y);
    const float eG = fexp2(zB.x), eO = fexp2(zB.y);
    const float f   = frcp(1.0f + eF);
    const float pig = (1.0f + eI) * (1.0f + eG);
    cm = f * cm + frcp(-0.69314718056f * pig);   // c' = f*c + i*g  (scaled by SS)
    const float ec = fexp2(cm);
    return frcp((1.0f + eO) * (1.0f + ec));
}

__global__ __launch_bounds__(256) __attribute__((amdgpu_waves_per_eu(1, 1)))
void fused_lstm3(const float* __restrict__ x,
                 const float* __restrict__ wk1, const float* __restrict__ wr1,
                 const float* __restrict__ b1,
                 const float* __restrict__ wk2, const float* __restrict__ wr2,
                 const float* __restrict__ b2,
                 const float* __restrict__ wdn, const float* __restrict__ bdn,
                 float* __restrict__ out)
{
    const float SS = -1.44269504088896f;         // -log2(e), folded into all gate weights

    // LSTM2 weights in LDS, gate-paired: row k=0..8 -> wk2 row k (input y4[k]),
    // row k=9..17 -> wr2 row k-9 (input h2[k-9]), row 18 -> bias.
    // Col j<9: pair (i,f) of unit j = cols (j, 9+j); col j>=9: pair (g,o) of unit j-9.
    __shared__ alignas(16) f32x2 Wl[19][18];

    const int tid = threadIdx.x;
#pragma unroll
    for (int it = 0; it < 2; ++it) {
        const int idx = tid + it * 256;
        if (idx < 342) {
            const int k = idx / 18, j = idx - k * 18;
            const int m  = (j < 9) ? j : j - 9;
            const int c0 = (j < 9) ? m : 18 + m;
            const int c1 = (j < 9) ? 9 + m : 27 + m;
            float v0, v1;
            if (k < 9)       { v0 = wk2[k * 36 + c0];       v1 = wk2[k * 36 + c1]; }
            else if (k < 18) { v0 = wr2[(k - 9) * 36 + c0]; v1 = wr2[(k - 9) * 36 + c1]; }
            else             { v0 = b2[c0];                 v1 = b2[c1]; }
            f32x2 w; w.x = v0 * SS; w.y = v1 * SS;
            Wl[k][j] = w;
        }
    }
    __syncthreads();

    // ---- chain assignment: wave w = blk*4+wv, s = w>>4 (chunk), b = (w&15)*64 + lane ----
    const int lane = tid & 63;
    const int w    = blockIdx.x * 4 + (tid >> 6);
    const int s    = w >> 4;                     // 0..63 (uniform per block!)
    const int b    = ((w & 15) << 6) | lane;     // 0..1023, exact cover

    const int t_start = s * CHUNK;
    const int t_end   = t_start + CHUNK;
    const int t0      = (s == 0) ? 0 : (t_start - WARMUP);

    // ---- LSTM1 weights in registers, gate-paired (shared across the 3 branches) ----
    // cols: i=0..2, f=3..5, g=6..8, o=9..11; pA[m]=(m,3+m), pB[m]=(6+m,9+m)
    f32x2 k1A[2][3], k1B[2][3], r1A[3][3], r1B[3][3], b1A[3], b1B[3];
#pragma unroll
    for (int m = 0; m < 3; ++m) {
#pragma unroll
        for (int r = 0; r < 2; ++r) {
            k1A[r][m].x = wk1[r * 12 + m] * SS;     k1A[r][m].y = wk1[r * 12 + 3 + m] * SS;
            k1B[r][m].x = wk1[r * 12 + 6 + m] * SS; k1B[r][m].y = wk1[r * 12 + 9 + m] * SS;
        }
#pragma unroll
        for (int r = 0; r < 3; ++r) {
            r1A[r][m].x = wr1[r * 12 + m] * SS;     r1A[r][m].y = wr1[r * 12 + 3 + m] * SS;
            r1B[r][m].x = wr1[r * 12 + 6 + m] * SS; r1B[r][m].y = wr1[r * 12 + 9 + m] * SS;
        }
        b1A[m].x = b1[m] * SS;     b1A[m].y = b1[3 + m] * SS;
        b1B[m].x = b1[6 + m] * SS; b1B[m].y = b1[9 + m] * SS;
    }
    // dense weights (9x3) + bias, pre-scaled
    f32x2 wdp[9], bdp; float wds[9], bds;
#pragma unroll
    for (int k = 0; k < 9; ++k) {
        wdp[k].x = wdn[k * 3] * SS; wdp[k].y = wdn[k * 3 + 1] * SS;
        wds[k]   = wdn[k * 3 + 2] * SS;
    }
    bdp.x = bdn[0] * SS; bdp.y = bdn[1] * SS; bds = bdn[2] * SS;

    // ---- state (all lane-local!) ----
    float y4[9], h2[9], c1m[9], c2m[9];
#pragma unroll
    for (int k = 0; k < 9; ++k) { y4[k] = 0.f; h2[k] = 0.f; c1m[k] = 0.f; c2m[k] = 0.f; }

    int xo = (b * SEQT + t0) * 6;                // 32-bit element offsets
    int oo = (b * SEQT + t_start) * 3;

    // depth-2 x prefetch ring (6 floats/step as 3x f32x2; 8B-aligned at any t)
    f32x2 xa0 = *(const f32x2*)(x + xo),     xa1 = *(const f32x2*)(x + xo + 2),
          xa2 = *(const f32x2*)(x + xo + 4);
    f32x2 xb0 = *(const f32x2*)(x + xo + 6), xb1 = *(const f32x2*)(x + xo + 8),
          xb2 = *(const f32x2*)(x + xo + 10);
    xo += 12;

#pragma unroll 1
    for (int t = t0; t < t_end; ++t) {
        // prefetch x(t+2); offset freezes at last row (re-reads row t_end-1 harmlessly)
        const f32x2 xc0 = *(const f32x2*)(x + xo);
        const f32x2 xc1 = *(const f32x2*)(x + xo + 2);
        const f32x2 xc2 = *(const f32x2*)(x + xo + 4);
        xo += ((t + 3) < t_end) ? 6 : 0;

        // ---- LSTM-1: 3 branches x 3 units, 18 z-pairs from OLD y4 ----
        f32x2 zA[3][3], zB[3][3];
#pragma unroll
        for (int p = 0; p < 3; ++p) {
            const f32x2 xi = (p == 0) ? xa0 : ((p == 1) ? xa1 : xa2);
            const float h0 = y4[3 * p], h1 = y4[3 * p + 1], h2v_ = y4[3 * p + 2];
#pragma unroll
            for (int m = 0; m < 3; ++m) {
                f32x2 a = b1A[m], bb = b1B[m];
                a  += k1A[0][m] * xi.x;  a  += k1A[1][m] * xi.y;
                bb += k1B[0][m] * xi.x;  bb += k1B[1][m] * xi.y;
                a  += r1A[0][m] * h0;    a  += r1A[1][m] * h1;    a  += r1A[2][m] * h2v_;
                bb += r1B[0][m] * h0;    bb += r1B[1][m] * h1;    bb += r1B[2][m] * h2v_;
                zA[p][m] = a; zB[p][m] = bb;
            }
        }
        // cells -> new y4
#pragma unroll
        for (int p = 0; p < 3; ++p)
#pragma unroll
            for (int m = 0; m < 3; ++m)
                y4[3 * p + m] = cellup(zA[p][m], zB[p][m], c1m[3 * p + m]);

        // ---- LSTM-2: 36 gates as 18 pk accumulators; weights broadcast from LDS ----
        f32x2 zp[18];
        {
            const f32x4* brow = (const f32x4*)&Wl[18][0];
#pragma unroll
            for (int j2 = 0; j2 < 9; ++j2) {
                const f32x4 w4 = brow[j2];
                zp[2 * j2].x     = w4.x; zp[2 * j2].y     = w4.y;
                zp[2 * j2 + 1].x = w4.z; zp[2 * j2 + 1].y = w4.w;
            }
        }
#pragma unroll
        for (int k = 0; k < 18; ++k) {
            const float in = (k < 9) ? y4[k] : h2[k - 9];
            const f32x4* row = (const f32x4*)&Wl[k][0];
#pragma unroll
            for (int j2 = 0; j2 < 9; ++j2) {
                const f32x4 w4 = row[j2];
                f32x2 lo; lo.x = w4.x; lo.y = w4.y;
                f32x2 hi; hi.x = w4.z; hi.y = w4.w;
                zp[2 * j2]     += lo * in;
                zp[2 * j2 + 1] += hi * in;
            }
        }
        // cells -> new h2
#pragma unroll
        for (int m = 0; m < 9; ++m)
            h2[m] = cellup(zp[m], zp[9 + m], c2m[m]);

        // ---- dense(3) + sigmoid + store ----
        f32x2 zd = bdp; float zs = bds;
#pragma unroll
        for (int k = 0; k < 9; ++k) { zd += wdp[k] * h2[k]; zs += wds[k] * h2[k]; }
        if (t >= t_start) {
            out[oo]     = frcp(1.0f + fexp2(zd.x));
            out[oo + 1] = frcp(1.0f + fexp2(zd.y));
            out[oo + 2] = frcp(1.0f + fexp2(zs));
            oo += 3;
        }

        xa0 = xb0; xa1 = xb1; xa2 = xb2;
        xb0 = xc0; xb1 = xc1; xb2 = xc2;
    }
}

extern "C" void kernel_launch(void* const* d_in, const int* in_sizes, int n_in,
                              void* d_out, int out_size, void* d_ws, size_t ws_size,
                              hipStream_t stream) {
    (void)in_sizes; (void)n_in; (void)d_ws; (void)ws_size; (void)out_size;
    // 1024 waves = 256 blocks x 4 waves = 1 block/CU, 1 wave/SIMD, zero tail
    hipLaunchKernelGGL(fused_lstm3, dim3(256), dim3(256), 0, stream,
                       (const float*)d_in[0],
                       (const float*)d_in[1], (const float*)d_in[2], (const float*)d_in[3],
                       (const float*)d_in[4], (const float*)d_in[5], (const float*)d_in[6],
                       (const float*)d_in[7], (const float*)d_in[8],
                       (float*)d_out);
}

// Round 8
// 271.946 us; speedup vs baseline: 4.5185x; 4.5185x over previous
//
#include <hip/hip_runtime.h>

// Fused 3-branch shared LSTM(H1=3) -> LSTM(H2=9) -> dense(3)+sigmoid, T=2048, B=1024.
// 9 lanes per chain (lane u: LSTM1 unit (u/3,u%3), LSTM2 unit u), 7 chains/wave.
// Weights in VGPRs pre-scaled by -log2(e); merged-rcp sigmoid cells; scaled cell state.
// Rotated gather order (slot k = unit (3p+k)%9) so slots 0..2 are own-branch h.
// R8: ONE WAVE PER SIMD (waves_per_eu(1,1), 64-thread blocks) so the full ~165-reg
// working set lives in arch VGPRs -> no v_accvgpr shuttle (R4-R7 evidence: arch VGPR
// = budget/2 whenever budget < demand). KC=6 -> 882 waves <= 1024 SIMDs, one round,
// no stragglers. Steps/wave <= 406 (342 chunk + 64 warmup).

#define BATCH  1024
#define SEQT   2048
#define KC     6
#define WPC    147    // ceil(1024/7) waves per chunk slot
#define WARMUP 64

typedef float f32x2 __attribute__((ext_vector_type(2)));

__device__ __forceinline__ float fexp2(float v) { return __builtin_amdgcn_exp2f(v); }
__device__ __forceinline__ float frcp(float v)  { return __builtin_amdgcn_rcpf(v); }
__device__ __forceinline__ float bperm(int addr, float v) {
    return __int_as_float(__builtin_amdgcn_ds_bpermute(addr, __float_as_int(v)));
}

__global__ __launch_bounds__(64) __attribute__((amdgpu_waves_per_eu(1, 1)))
void fused_lstm3(const float* __restrict__ x,
                 const float* __restrict__ wk1, const float* __restrict__ wr1,
                 const float* __restrict__ b1,
                 const float* __restrict__ wk2, const float* __restrict__ wr2,
                 const float* __restrict__ b2,
                 const float* __restrict__ wdn, const float* __restrict__ bdn,
                 float* __restrict__ out)
{
    const int lane  = threadIdx.x;               // 64-thread block = exactly one wave
    const int group = lane / 9;                  // 7 groups of 9 lanes; lane 63 idle
    const bool act  = (group < 7);
    const int u     = act ? (lane - group * 9) : 0;

    const int wv = blockIdx.x;                   // one wave per block
    int s        = wv / WPC;
    const int bw = wv - s * WPC;
    const bool vs = (s < KC);
    if (!vs) s = KC - 1;
    int b = bw * 7 + (act ? group : 6);
    const bool vb = (b < BATCH);
    if (!vb) b = BATCH - 1;
    const bool do_store = vs && vb && act && (u < 3);

    const int t_start = (SEQT * s) / KC;
    const int t_end   = (SEQT * (s + 1)) / KC;
    const int t0      = (t_start > WARMUP) ? (t_start - WARMUP) : 0;

    const int p  = u / 3;                        // branch index
    const int q  = u - p * 3;                    // unit within branch

    const float SS = -1.44269504088896f;         // -log2(e) folded into gate weights

    // rotated gather addresses: slot k <- unit (3p+k)%9 of this group
    int offv[9];
#pragma unroll
    for (int k = 0; k < 9; ++k) {
        int j = 3 * p + k; j = (j >= 9) ? j - 9 : j;
        offv[k] = (group * 9 + j) << 2;
    }

    // ---- per-lane weights, pre-scaled, packed in gate-pairs (i,f) and (g,o) ----
    f32x2 w1a[2], w1b[2], w1h[2][3], b1p[2];
    f32x2 w2xp[2][9], w2hp[2][9], b2p[2];
    float wdk[9], dbu;
#pragma unroll
    for (int pr = 0; pr < 2; ++pr) {
        const int g0 = 2 * pr, g1 = 2 * pr + 1;
        const int c0 = g0 * 3 + q, c1 = g1 * 3 + q;      // LSTM1 cols (gate-major i,f,g,o)
        w1a[pr].x = wk1[c0] * SS;       w1a[pr].y = wk1[c1] * SS;
        w1b[pr].x = wk1[12 + c0] * SS;  w1b[pr].y = wk1[12 + c1] * SS;
#pragma unroll
        for (int k = 0; k < 3; ++k) {
            w1h[pr][k].x = wr1[k * 12 + c0] * SS;
            w1h[pr][k].y = wr1[k * 12 + c1] * SS;
        }
        b1p[pr].x = b1[c0] * SS;  b1p[pr].y = b1[c1] * SS;
        const int d0 = g0 * 9 + u, d1 = g1 * 9 + u;      // LSTM2 cols
#pragma unroll
        for (int k = 0; k < 9; ++k) {
            const int jj = (offv[k] >> 2) - group * 9;   // permuted unit index
            w2xp[pr][k].x = wk2[jj * 36 + d0] * SS;
            w2xp[pr][k].y = wk2[jj * 36 + d1] * SS;
            w2hp[pr][k].x = wr2[jj * 36 + d0] * SS;
            w2hp[pr][k].y = wr2[jj * 36 + d1] * SS;
        }
        b2p[pr].x = b2[d0] * SS;  b2p[pr].y = b2[d1] * SS;
    }
    {
        const int d = (u < 3) ? u : 0;
#pragma unroll
        for (int k = 0; k < 9; ++k) {
            const int jj = (offv[k] >> 2) - group * 9;
            wdk[k] = wdn[jj * 3 + d] * SS;
        }
        dbu = bdn[d] * SS;
    }

    // ---- state ----
    float cm1 = 0.f, cm2 = 0.f;                  // scaled cell states (-log2e * c)
    float y4g[9], h2g[9];
#pragma unroll
    for (int k = 0; k < 9; ++k) { y4g[k] = 0.f; h2g[k] = 0.f; }

    // 32-bit element offsets from SGPR bases (x = 48 MB, out = 25 MB: both < 4 GB)
    int xo = (b * SEQT + t0) * 6 + 2 * p;
    int oo = (b * SEQT + t_start) * 3 + u;

    // depth-2 prefetch ring (chunk length >= 341, so +12 is safe)
    float2 xv0 = *(const float2*)(x + xo);
    float2 xv1 = *(const float2*)(x + xo + 6);
    xo += 12;

#pragma unroll 2
    for (int t = t0; t < t_end; ++t) {
        // prefetch x for t+2 (offset freezes near chunk end)
        const float2 xn = *(const float2*)(x + xo);
        xo += ((t + 3) < t_end) ? 6 : 0;

        // ---- LSTM-1 (slots 0..2 are this lane's branch h); pk_fma pairs ----
        f32x2 zA = b1p[0], zB = b1p[1];
        zA += w1a[0] * xv0.x;    zB += w1a[1] * xv0.x;
        zA += w1b[0] * xv0.y;    zB += w1b[1] * xv0.y;
        zA += w1h[0][0] * y4g[0]; zB += w1h[1][0] * y4g[0];
        zA += w1h[0][1] * y4g[1]; zB += w1h[1][1] * y4g[1];
        zA += w1h[0][2] * y4g[2]; zB += w1h[1][2] * y4g[2];
        {
            const float eI = fexp2(zA.x), eF = fexp2(zA.y);
            const float eG = fexp2(zB.x), eO = fexp2(zB.y);
            const float f   = frcp(1.0f + eF);
            const float pig = (1.0f + eI) * (1.0f + eG);
            cm1 = f * cm1 + frcp(-0.69314718056f * pig);
            const float ec = fexp2(cm1);
            const float h1v = frcp((1.0f + eO) * (1.0f + ec));

            // ---- issue y4 gathers immediately (rotated order) ----
#pragma unroll
            for (int k = 0; k < 9; ++k) y4g[k] = bperm(offv[k], h1v);
        }

        // ---- dense + store for step t-1 (old h2g; fills DS window) ----
        if (t > t_start) {
            float a0 = dbu, a1 = 0.f;
#pragma unroll
            for (int k = 0; k < 4; ++k) a0 += h2g[k] * wdk[k];
#pragma unroll
            for (int k = 4; k < 9; ++k) a1 += h2g[k] * wdk[k];
            const float yv = frcp(1.0f + fexp2(a0 + a1));
            if (do_store) out[oo] = yv;
            oo += 3;
        }

        // ---- zh: LSTM2 h-recurrence partials (old h2g; fills DS window) ----
        f32x2 zhA = b2p[0], zhB = b2p[1];
        f32x2 zhA1 = (f32x2)(0.f), zhB1 = (f32x2)(0.f);
#pragma unroll
        for (int k = 0; k < 4; ++k) { zhA  += w2hp[0][k] * h2g[k]; zhB  += w2hp[1][k] * h2g[k]; }
#pragma unroll
        for (int k = 4; k < 9; ++k) { zhA1 += w2hp[0][k] * h2g[k]; zhB1 += w2hp[1][k] * h2g[k]; }
        zhA += zhA1; zhB += zhB1;

        // ---- finish LSTM2 (waits on y4 gathers here) ----
        f32x2 z2A = zhA, z2B = zhB;
        f32x2 z2A1 = (f32x2)(0.f), z2B1 = (f32x2)(0.f);
#pragma unroll
        for (int k = 0; k < 4; ++k) { z2A  += w2xp[0][k] * y4g[k]; z2B  += w2xp[1][k] * y4g[k]; }
#pragma unroll
        for (int k = 4; k < 9; ++k) { z2A1 += w2xp[0][k] * y4g[k]; z2B1 += w2xp[1][k] * y4g[k]; }
        z2A += z2A1; z2B += z2B1;
        {
            const float eI = fexp2(z2A.x), eF = fexp2(z2A.y);
            const float eG = fexp2(z2B.x), eO = fexp2(z2B.y);
            const float f   = frcp(1.0f + eF);
            const float pig = (1.0f + eI) * (1.0f + eG);
            cm2 = f * cm2 + frcp(-0.69314718056f * pig);
            const float ec = fexp2(cm2);
            const float h2v = frcp((1.0f + eO) * (1.0f + ec));

            // ---- issue h2 gathers immediately ----
#pragma unroll
            for (int k = 0; k < 9; ++k) h2g[k] = bperm(offv[k], h2v);
        }

        xv0 = xv1; xv1 = xn;
    }

    // ---- epilogue: dense + store for final step (t_end-1) ----
    {
        float a0 = dbu, a1 = 0.f;
#pragma unroll
        for (int k = 0; k < 4; ++k) a0 += h2g[k] * wdk[k];
#pragma unroll
        for (int k = 4; k < 9; ++k) a1 += h2g[k] * wdk[k];
        const float yv = frcp(1.0f + fexp2(a0 + a1));
        if (do_store) out[oo] = yv;
    }
}

extern "C" void kernel_launch(void* const* d_in, const int* in_sizes, int n_in,
                              void* d_out, int out_size, void* d_ws, size_t ws_size,
                              hipStream_t stream) {
    (void)in_sizes; (void)n_in; (void)d_ws; (void)ws_size; (void)out_size;
    // 882 one-wave blocks (64 thr): <= 1024 SIMDs -> single round, no stragglers
    hipLaunchKernelGGL(fused_lstm3, dim3(KC * WPC), dim3(64), 0, stream,
                       (const float*)d_in[0],
                       (const float*)d_in[1], (const float*)d_in[2], (const float*)d_in[3],
                       (const float*)d_in[4], (const float*)d_in[5], (const float*)d_in[6],
                       (const float*)d_in[7], (const float*)d_in[8],
                       (float*)d_out);
}